// Round 12
// baseline (156.247 us; speedup 1.0000x reference)
//
#include <hip/hip_runtime.h>

#define T_N   131072
#define K_N   64
#define L_C   32               /* rows per CHAIN */
#define BLK   64               /* rows per block = 2 chains */
#define N_BL  (T_N / BLK)      /* 2048 blocks per direction */
#define F_N   8
#define WARM  24
#define EPS_F 1e-10f
#define OBS_MAX ((T_N - 1) * F_N)

#define LOG2E 1.4426950408889634f
#define NL2E  (-0.72134752044448170f)
#define LN2   0.6931471805599453f
#define LN2PI 1.8378770664093453f
/* warm-up-only emission pre-scale 2^16 (round-2: store phase must stay at
   RAW emission scale to reproduce reference EPS saturation).
   WARM=24: r9 proved WARM=16 passes (9.3e-3); 24 adds lambda^8~0.03 margin
   -> expect ~6.6e-3. ILP-2 (round-12): wall = VALU-time/VALUBusy held
   across r7/r8/r11 (127 ns/chain-step); VALUBusy capped by chains/SIMD.
   8 independent waves needs <=64 regs (r9: catastrophic spill). Instead:
   2 chains/wave SHARING the 64-reg Tq matrix -> 8 chains/SIMD at ~120 regs
   under the (64,2)->128 budget (2x-rule, r10/r11). */
#define EMSC  16.0f

typedef float v2f __attribute__((ext_vector_type(2)));
typedef __attribute__((ext_vector_type(4))) float f32x4;

template <int CTRL>
__device__ __forceinline__ float dpp_add(float x) {
  int y = __builtin_amdgcn_update_dpp(0, __float_as_int(x), CTRL, 0xF, 0xF, true);
  return x + __int_as_float(y);
}
__device__ __forceinline__ float wave_sum64(float x) {
  x = dpp_add<0x111>(x);
  x = dpp_add<0x112>(x);
  x = dpp_add<0x114>(x);
  x = dpp_add<0x118>(x);
  x = dpp_add<0x142>(x);
  x = dpp_add<0x143>(x);
  return __int_as_float(__builtin_amdgcn_readlane(__float_as_int(x), 63));
}

#define PKFMA(a, b, c) __builtin_elementwise_fma(a, b, c)
#define RCP(x) __builtin_amdgcn_rcpf(x)

__device__ __forceinline__ float em_pk(const float4& xa, const float4& xb,
                                       const v2f civ2[4], const v2f cmiv2[4],
                                       float cc) {
  v2f x0 = {xa.x, xa.y}, x1 = {xa.z, xa.w};
  v2f x2 = {xb.x, xb.y}, x3 = {xb.z, xb.w};
  v2f a0 = {cc, 0.f}, a1 = {0.f, 0.f};
  a0 = PKFMA(x0, PKFMA(x0, civ2[0], cmiv2[0]), a0);
  a1 = PKFMA(x1, PKFMA(x1, civ2[1], cmiv2[1]), a1);
  a0 = PKFMA(x2, PKFMA(x2, civ2[2], cmiv2[2]), a0);
  a1 = PKFMA(x3, PKFMA(x3, civ2[3], cmiv2[3]), a1);
  v2f s = a0 + a1;
  return __builtin_amdgcn_exp2f(s.x + s.y);
}

/* 64x64 matvec: quarter-read + partial-sum exchange (r7/r8 structure),
   parameterized by state table so two chains can interleave. */
#define MATVEC(VT, VQP, VV, MOUT)                                             \
  {                                                                           \
    VT[lane] = (VV);                                                          \
    f32x4 q0_ = VQP[0], q1_ = VQP[1], q2_ = VQP[2], q3_ = VQP[3];             \
    v2f q0l_ = {q0_.x, q0_.y}, q0h_ = {q0_.z, q0_.w};                         \
    v2f q1l_ = {q1_.x, q1_.y}, q1h_ = {q1_.z, q1_.w};                         \
    v2f q2l_ = {q2_.x, q2_.y}, q2h_ = {q2_.z, q2_.w};                         \
    v2f q3l_ = {q3_.x, q3_.y}, q3h_ = {q3_.z, q3_.w};                         \
    float X0_, X1_, X2_, X3_;                                                 \
    _Pragma("unroll")                                                         \
    for (int d_ = 0; d_ < 4; ++d_) {                                          \
      v2f aA_ = {0.f, 0.f}, aB_ = {0.f, 0.f};                                 \
      aA_ = PKFMA(q0l_, Tq[d_][0], aA_);                                      \
      aB_ = PKFMA(q0h_, Tq[d_][1], aB_);                                      \
      aA_ = PKFMA(q1l_, Tq[d_][2], aA_);                                      \
      aB_ = PKFMA(q1h_, Tq[d_][3], aB_);                                      \
      aA_ = PKFMA(q2l_, Tq[d_][4], aA_);                                      \
      aB_ = PKFMA(q2h_, Tq[d_][5], aB_);                                      \
      aA_ = PKFMA(q3l_, Tq[d_][6], aA_);                                      \
      aB_ = PKFMA(q3h_, Tq[d_][7], aB_);                                      \
      v2f s_ = aA_ + aB_;                                                     \
      float xs_ = s_.x + s_.y;                                                \
      if (d_ == 0) X0_ = xs_;                                                 \
      else if (d_ == 1) X1_ = xs_;                                            \
      else if (d_ == 2) X2_ = xs_;                                            \
      else X3_ = xs_;                                                         \
    }                                                                         \
    float e1_ = __int_as_float(                                               \
        __builtin_amdgcn_ds_swizzle(__float_as_int(X1_), 0x401F));            \
    float e2_ = __int_as_float(                                               \
        __builtin_amdgcn_ds_bpermute(a32, __float_as_int(X2_)));              \
    float e3_ = __int_as_float(                                               \
        __builtin_amdgcn_ds_bpermute(a48, __float_as_int(X3_)));              \
    MOUT = (X0_ + e1_) + (e2_ + e3_);                                         \
  }

/* ---- per-chain step macros ---- */
#define FWSTEP(VT, VQP, V, XA, XB, OFF)                                       \
  {                                                                           \
    float4 nxa = *reinterpret_cast<const float4*>(obs + (OFF) + F_N);         \
    float4 nxb = *reinterpret_cast<const float4*>(obs + (OFF) + F_N + 4);     \
    float m;                                                                  \
    MATVEC(VT, VQP, V, m)                                                     \
    float e = em_pk(XA, XB, civ2, cmiv2, cw);                                 \
    V = m * e; XA = nxa; XB = nxb; OFF += F_N;                                \
  }

#define FSSTEP(VT, VQP, V, S, R, XA, XB, OFF, OUT)                            \
  {                                                                           \
    int offn = (OFF) + F_N; offn = (offn > OBS_MAX) ? OBS_MAX : offn;         \
    float4 nxa = *reinterpret_cast<const float4*>(obs + offn);                \
    float4 nxb = *reinterpret_cast<const float4*>(obs + offn + 4);            \
    float m;                                                                  \
    MATVEC(VT, VQP, V, m)                                                     \
    alpha[OUT] = V * R; OUT += K_N;                                           \
    float e = em_pk(XA, XB, civ2, cmiv2, c0);                                 \
    float vn = m * (R * e);                                                   \
    S = wave_sum64(vn);                                                       \
    R = RCP(S + EPS_F);                                                       \
    V = vn; XA = nxa; XB = nxb; OFF = offn;                                   \
  }

#define BWSTEP(VT, VQP, W, XA, XB, OFF)                                       \
  {                                                                           \
    float4 nxa = *reinterpret_cast<const float4*>(obs + (OFF) - F_N);         \
    float4 nxb = *reinterpret_cast<const float4*>(obs + (OFF) - F_N + 4);     \
    float m;                                                                  \
    MATVEC(VT, VQP, W, m)                                                     \
    float e = em_pk(XA, XB, civ2, cmiv2, cw);                                 \
    W = m * e; XA = nxa; XB = nxb; OFF -= F_N;                                \
  }

#define BTRANS(VT, VQP, W, U, S, R, XA, XB, OFF)                              \
  {                                                                           \
    float m;                                                                  \
    MATVEC(VT, VQP, W, m)                                                     \
    float Sm = wave_sum64(m);                                                 \
    U = m * RCP(Sm);                                                          \
    float e = em_pk(XA, XB, civ2, cmiv2, c0);                                 \
    W = U * e;                                                                \
    S = wave_sum64(U);                                                        \
    R = RCP(S + EPS_F);                                                       \
    int offn = (OFF) - F_N; offn = (offn < 0) ? 0 : offn;                     \
    XA = *reinterpret_cast<const float4*>(obs + offn);                        \
    XB = *reinterpret_cast<const float4*>(obs + offn + 4);                    \
    OFF = offn;                                                               \
  }

#define BSSTEP(VT, VQP, W, U, S, R, XA, XB, OFF, OUT, DOST)                   \
  {                                                                           \
    int offn = (OFF) - F_N; offn = (offn < 0) ? 0 : offn;                     \
    float4 nxa = *reinterpret_cast<const float4*>(obs + offn);                \
    float4 nxb = *reinterpret_cast<const float4*>(obs + offn + 4);            \
    float m;                                                                  \
    MATVEC(VT, VQP, W, m)                                                     \
    if (DOST) { betaout[OUT] = U * R; OUT -= K_N; }                           \
    float u2 = m * R;                                                         \
    float e = em_pk(XA, XB, civ2, cmiv2, c0);                                 \
    W = u2 * e;                                                               \
    S = wave_sum64(u2);                                                       \
    R = RCP(S + EPS_F);                                                       \
    U = u2; XA = nxa; XB = nxb; OFF = offn;                                   \
  }

extern "C" __global__ void __launch_bounds__(64, 2)
hdphmm_fb(const float* __restrict__ obs,
          const float* __restrict__ beta_logits,
          const float* __restrict__ pi_logits,
          const float* __restrict__ means,
          const float* __restrict__ log_vars,
          float* __restrict__ out) {
  const int lane = threadIdx.x;
  const int bid  = blockIdx.x;
  const int g16  = (lane >> 4) << 4;
  const int a32  = ((lane ^ 32) & 63) << 2;
  const int a48  = ((lane ^ 48) & 63) << 2;

  __shared__ __align__(8) float2 sstat[K_N];
  __shared__ float sb[K_N];
  __shared__ __align__(16) float vtabA[K_N];
  __shared__ __align__(16) float vtabB[K_N];
  const f32x4* vqA = reinterpret_cast<const f32x4*>(vtabA) + (lane >> 4) * 4;
  const f32x4* vqB = reinterpret_cast<const f32x4*>(vtabB) + (lane >> 4) * 4;

  float* alpha   = out;
  float* betaout = out + (size_t)T_N * K_N;

  v2f civ2[4], cmiv2[4];
  float c0, cw;
  {
    const float4* mp = reinterpret_cast<const float4*>(means + lane * F_N);
    const float4* lp = reinterpret_cast<const float4*>(log_vars + lane * F_N);
    float4 m0 = mp[0], m1 = mp[1];
    float4 l0 = lp[0], l1 = lp[1];
    float mu[8] = {m0.x, m0.y, m0.z, m0.w, m1.x, m1.y, m1.z, m1.w};
    float lv[8] = {l0.x, l0.y, l0.z, l0.w, l1.x, l1.y, l1.z, l1.w};
    float cst = F_N * LN2PI;
#pragma unroll
    for (int f = 0; f < 8; ++f) {
      float iv = __builtin_amdgcn_exp2f(-lv[f] * LOG2E);
      cst += lv[f] + mu[f] * mu[f] * iv;
      float cf  = NL2E * iv;
      civ2[f >> 1][f & 1]  = cf;
      cmiv2[f >> 1][f & 1] = -2.0f * mu[f] * cf;
    }
    c0 = NL2E * cst;
    cw = c0 + EMSC;
  }

  {
    const float4* pr4 = reinterpret_cast<const float4*>(pi_logits + lane * K_N);
    float mx = -3.0e38f;
#pragma unroll
    for (int k = 0; k < 16; ++k) {
      float4 r = pr4[k];
      mx = fmaxf(mx, fmaxf(fmaxf(r.x, r.y), fmaxf(r.z, r.w)));
    }
    float s = 0.0f;
#pragma unroll
    for (int k = 0; k < 16; ++k) {
      float4 r = pr4[k];
      s += __builtin_amdgcn_exp2f((r.x - mx) * LOG2E);
      s += __builtin_amdgcn_exp2f((r.y - mx) * LOG2E);
      s += __builtin_amdgcn_exp2f((r.z - mx) * LOG2E);
      s += __builtin_amdgcn_exp2f((r.w - mx) * LOG2E);
    }
    sstat[lane] = make_float2(mx, RCP(s));
  }
  __syncthreads();

  v2f Tq[4][8];

  if (bid < N_BL) {
    /* ================= FORWARD pair: rows [64b,64b+32) (A), [64b+32,64b+64) (B) */
    const int b = bid;
#pragma unroll
    for (int d = 0; d < 4; ++d) {
      int row = lane ^ (16 * d);
#pragma unroll
      for (int c = 0; c < 8; ++c) {
        int k0 = g16 + 2 * c, k1 = k0 + 1;
        float2 s0 = sstat[k0], s1 = sstat[k1];
        float p0 = pi_logits[(size_t)k0 * K_N + row];
        float p1 = pi_logits[(size_t)k1 * K_N + row];
        Tq[d][c] = (v2f){__builtin_amdgcn_exp2f((p0 - s0.x) * LOG2E) * s0.y,
                         __builtin_amdgcn_exp2f((p1 - s1.x) * LOG2E) * s1.y};
      }
    }

    const int rowA = b * BLK, rowB = rowA + L_C;
    float vA, vB;
    int offA, offB;
    const bool aw = (b != 0);
    if (aw) {
      const int t0 = rowA - WARM;
      const float4* xp = reinterpret_cast<const float4*>(obs + t0 * F_N);
      vA = em_pk(xp[0], xp[1], civ2, cmiv2, cw);
      offA = (t0 + 1) * F_N;
    } else {
      /* exact stick-breaking init at RAW scale */
      float bl = beta_logits[lane];
      float ex = __builtin_amdgcn_exp2f(-bl * LOG2E);
      float bw = RCP(1.0f + ex);
      sb[lane] = 1.0f - bw;
      __syncthreads();
      float pr = 1.0f;
#pragma unroll
      for (int i = 0; i < 64; ++i) {
        float qv = sb[i];
        pr = (i < lane) ? pr * qv : pr;
      }
      float4 x0 = reinterpret_cast<const float4*>(obs)[0];
      float4 x1 = reinterpret_cast<const float4*>(obs)[1];
      vA = bw * pr * em_pk(x0, x1, civ2, cmiv2, c0);
      offA = 1 * F_N;
    }
    {
      const int t0b = rowB - WARM;
      const float4* xp = reinterpret_cast<const float4*>(obs + t0b * F_N);
      vB = em_pk(xp[0], xp[1], civ2, cmiv2, cw);
      offB = (t0b + 1) * F_N;
    }
    float4 xaA, xbA, xaB, xbB;
    xaA = *reinterpret_cast<const float4*>(obs + offA);
    xbA = *reinterpret_cast<const float4*>(obs + offA + 4);
    xaB = *reinterpret_cast<const float4*>(obs + offB);
    xbB = *reinterpret_cast<const float4*>(obs + offB + 4);

    /* warm: 24 = 3 x 8, rescale each 8; A predicated (uniform) */
    if (aw) {
#pragma unroll 1
      for (int o = 0; o < 3; ++o) {
#pragma unroll
        for (int i = 0; i < 8; ++i) {
          FWSTEP(vtabA, vqA, vA, xaA, xbA, offA)
          FWSTEP(vtabB, vqB, vB, xaB, xbB, offB)
        }
        float SwA = wave_sum64(vA); vA *= RCP(SwA);
        float SwB = wave_sum64(vB); vB *= RCP(SwB);
      }
    } else {
#pragma unroll 1
      for (int o = 0; o < 3; ++o) {
#pragma unroll
        for (int i = 0; i < 8; ++i) {
          FWSTEP(vtabB, vqB, vB, xaB, xbB, offB)
        }
        float SwB = wave_sum64(vB); vB *= RCP(SwB);
      }
    }

    float SA = wave_sum64(vA), SB = wave_sum64(vB);
    float rA = RCP(SA + EPS_F), rB = RCP(SB + EPS_F);
    int outA = rowA * K_N + lane, outB = rowB * K_N + lane;

#pragma unroll 1
    for (int it = 0; it < L_C - 1; ++it) {
      FSSTEP(vtabA, vqA, vA, SA, rA, xaA, xbA, offA, outA)
      FSSTEP(vtabB, vqB, vB, SB, rB, xaB, xbB, offB, outB)
    }
    alpha[outA] = vA * rA;
    alpha[outB] = vB * rB;
    if (b == N_BL - 1 && lane == 0) {
      float sl = SB * rB + EPS_F;
      out[(size_t)2 * T_N * K_N] = __builtin_amdgcn_logf(sl) * LN2;
    }
  } else {
    /* ================= BACKWARD pair: A = upper [64b+32,64b+64), B = lower */
    const int b = bid - N_BL;
#pragma unroll
    for (int d = 0; d < 4; ++d) {
      int row = lane ^ (16 * d);
      float2 st = sstat[row];
      const float4* rp =
          reinterpret_cast<const float4*>(pi_logits + (size_t)row * K_N + g16);
#pragma unroll
      for (int c4 = 0; c4 < 4; ++c4) {
        float4 r = rp[c4];
        Tq[d][2 * c4] =
            (v2f){__builtin_amdgcn_exp2f((r.x - st.x) * LOG2E) * st.y,
                  __builtin_amdgcn_exp2f((r.y - st.x) * LOG2E) * st.y};
        Tq[d][2 * c4 + 1] =
            (v2f){__builtin_amdgcn_exp2f((r.z - st.x) * LOG2E) * st.y,
                  __builtin_amdgcn_exp2f((r.w - st.x) * LOG2E) * st.y};
      }
    }

    const int t_loB = b * BLK;            /* B stores [t_loB, t_loB+32) */
    const int t_loA = t_loB + L_C;        /* A stores [t_loA, t_loA+32) */
    const bool last = (b == N_BL - 1);
    const bool aw   = !last;              /* A warm active (generic) */

    int t_topA = t_loA + L_C - 1 + WARM;  /* 64b+87 */
    if (t_topA > T_N - 1) t_topA = T_N - 1;
    const int s_topA = last ? T_N - 2 : t_loA + L_C - 1;
    const int t_topB = t_loB + L_C - 1 + WARM;   /* 64b+55, never clamps */
    const int s_topB = t_loB + L_C - 1;

    float wA, wB;
    {
      const float4* xp = reinterpret_cast<const float4*>(obs + t_topA * F_N);
      wA = em_pk(xp[0], xp[1], civ2, cmiv2, cw);
    }
    {
      const float4* xp = reinterpret_cast<const float4*>(obs + t_topB * F_N);
      wB = em_pk(xp[0], xp[1], civ2, cmiv2, cw);
    }
    if (last && lane == 0) { /* bT anchor row, full row written below */ }
    if (last)
      betaout[(size_t)(T_N - 1) * K_N + lane] = 1.0f;

    int offA = (t_topA - 1) * F_N, offB = (t_topB - 1) * F_N;
    float4 xaA, xbA, xaB, xbB;
    xaA = *reinterpret_cast<const float4*>(obs + offA);
    xbA = *reinterpret_cast<const float4*>(obs + offA + 4);
    xaB = *reinterpret_cast<const float4*>(obs + offB);
    xbB = *reinterpret_cast<const float4*>(obs + offB + 4);

    /* warm: pw = 23 = 2x8 + 7; A predicated off for last block (pwA=0) */
    if (aw) {
#pragma unroll 1
      for (int o = 0; o < 2; ++o) {
#pragma unroll
        for (int i = 0; i < 8; ++i) {
          BWSTEP(vtabA, vqA, wA, xaA, xbA, offA)
          BWSTEP(vtabB, vqB, wB, xaB, xbB, offB)
        }
        float SwA = wave_sum64(wA); wA *= RCP(SwA);
        float SwB = wave_sum64(wB); wB *= RCP(SwB);
      }
#pragma unroll 1
      for (int it = 0; it < 7; ++it) {
        BWSTEP(vtabA, vqA, wA, xaA, xbA, offA)
        BWSTEP(vtabB, vqB, wB, xaB, xbB, offB)
      }
    } else {
#pragma unroll 1
      for (int o = 0; o < 2; ++o) {
#pragma unroll
        for (int i = 0; i < 8; ++i) {
          BWSTEP(vtabB, vqB, wB, xaB, xbB, offB)
        }
        float SwB = wave_sum64(wB); wB *= RCP(SwB);
      }
#pragma unroll 1
      for (int it = 0; it < 7; ++it) {
        BWSTEP(vtabB, vqB, wB, xaB, xbB, offB)
      }
    }

    /* transitions: exact direction normalize, switch to RAW-scale em */
    float uA, SA, rA, uB, SB, rB;
    BTRANS(vtabA, vqA, wA, uA, SA, rA, xaA, xbA, offA)
    BTRANS(vtabB, vqB, wB, uB, SB, rB, xaB, xbB, offB)

    int outA = s_topA * K_N + lane, outB = s_topB * K_N + lane;
    const int snA = last ? (L_C - 2) : (L_C - 1);   /* 30 or 31 */

#pragma unroll 1
    for (int it = 0; it < L_C - 1; ++it) {
      BSSTEP(vtabA, vqA, wA, uA, SA, rA, xaA, xbA, offA, outA, (it < snA))
      BSSTEP(vtabB, vqB, wB, uB, SB, rB, xaB, xbB, offB, outB, true)
    }
    betaout[t_loA * K_N + lane] = uA * rA;
    betaout[t_loB * K_N + lane] = uB * rB;
  }
}

extern "C" void kernel_launch(void* const* d_in, const int* in_sizes, int n_in,
                              void* d_out, int out_size, void* d_ws, size_t ws_size,
                              hipStream_t stream) {
  (void)in_sizes; (void)n_in; (void)out_size; (void)d_ws; (void)ws_size;
  const float* obs  = (const float*)d_in[0];
  const float* bl   = (const float*)d_in[1];
  const float* pi   = (const float*)d_in[2];
  const float* mns  = (const float*)d_in[3];
  const float* lvs  = (const float*)d_in[4];
  hipLaunchKernelGGL(hdphmm_fb, dim3(2 * N_BL), dim3(64), 0, stream,
                     obs, bl, pi, mns, lvs, (float*)d_out);
}